// Round 6
// baseline (274.781 us; speedup 1.0000x reference)
//
#include <hip/hip_runtime.h>
#include <hip/hip_bf16.h>
#include <math.h>

#define BB 512
#define DD 128
#define CC 100000

#define BLK_M 64
#define BLK_N 64
#define LDA 136                 // bf16 units; 272B row stride -> 2-way (free) b128 frag reads
#define LDB 136

__device__ __constant__ const float COS_M  =  0.87758256189037271612f;  // cos(0.5)
__device__ __constant__ const float SIN_M  =  0.47942553860420300538f;  // sin(0.5)
__device__ __constant__ const float THRESH = -0.87758256189037271612f;  // cos(pi-0.5)
__device__ __constant__ const float MMc    =  0.23971276930210150269f;  // sin(0.5)*0.5
#define SCALE_F 64.0f
#define ALPHA_F 1.2f

typedef __attribute__((ext_vector_type(8))) short short8;
typedef __attribute__((ext_vector_type(4))) float float4v;

__device__ inline float waveReduceSum(float v) {
    #pragma unroll
    for (int off = 32; off > 0; off >>= 1)
        v += __shfl_xor(v, off, 64);
    return v;
}

// --- K1: fused feats-normalize (-> bf16 exb) + per-row a_lb (full fp32) ---
__global__ void k_prep(const float* __restrict__ feats, const float* __restrict__ w,
                       const int* __restrict__ labels,
                       __hip_bfloat16* __restrict__ exb, float* __restrict__ alb) {
    int b = blockIdx.x;
    int lane = threadIdx.x;          // 64 threads, 2 floats each
    int lab = labels[b];
    float2 f = ((const float2*)(feats + b * DD))[lane];
    float2 g = ((const float2*)(w + (size_t)lab * DD))[lane];
    float nf  = waveReduceSum(f.x * f.x + f.y * f.y);
    float dot = waveReduceSum(f.x * g.x + f.y * g.y);
    float nw  = waveReduceSum(g.x * g.x + g.y * g.y);
    float rn = rsqrtf(nf);
    __hip_bfloat162 o;
    o.x = __float2bfloat16(f.x * rn);
    o.y = __float2bfloat16(f.y * rn);
    ((__hip_bfloat162*)(exb + b * DD))[lane] = o;
    if (lane == 0) {
        float c = dot * rsqrtf(nf * nw);
        float a;
        if (c > THRESH) {
            float cc = fminf(fmaxf(c, -1.0f), 1.0f);
            a = cc * COS_M - SIN_M * sqrtf(fmaxf(0.0f, 1.0f - cc * cc));  // cos(acos+M)
        } else {
            a = c - MMc;
        }
        alb[b] = a;
    }
}

// --- K2: column-tile kernel, 64 cols per block; baseline barrier pacing,
// transpose REMOVED via operand-swapped MFMA.
// 1563 blocks, 256 threads (4 waves), 4 blocks/CU (LDS 34,816 B).
// Per iter (8 row-tiles): stage A (2-way-free b128 writes) -> sync ->
// swapped MFMA D[class][batch] = mfma(cf, af):
//   col = lane&15 -> batch row bt*16+lrow;  row = lquad*4+e -> 4 CONSECUTIVE
//   classes (wave*16 + lquad*4 + e)  ==> acc quad IS the output float4.
// cf (this wave's 16-class fragments) hoisted outside the loop: 16 VGPRs.
// -> sync (af reads done; A reusable) -> register epilogue + plain cached
// float4 stores (the two waves sharing each 128B line store in the same
// barrier phase -> L2 merges to full lines before eviction).
// 2 barriers/iter (was 4); 20 LDS wave-ops/iter/wave (was 44).
__global__ __launch_bounds__(256, 4)
void k_main(const __hip_bfloat16* __restrict__ exb,
            const float* __restrict__ w,
            const float* __restrict__ alb,
            const int* __restrict__ labels,
            float* __restrict__ out) {
    __shared__ __align__(16) __hip_bfloat16 As[BLK_M][LDA];    // 17408 B
    __shared__ __align__(16) __hip_bfloat16 Bs[BLK_N][LDB];    // 17408 B

    int tid = threadIdx.x;
    int c0 = blockIdx.x * BLK_N;

    // ---- normalize BLK_N weight rows into Bs (4 threads per row) ----
    {
        int r = tid >> 2;            // 0..63
        int h = tid & 3;             // quarter-row: 32 floats
        int c = c0 + r;
        float4 buf[8];
        float ss = 0.f;
        if (c < CC) {
            const float4* src = (const float4*)(w + (size_t)c * DD + h * 32);
            #pragma unroll
            for (int j = 0; j < 8; j++) {
                buf[j] = src[j];
                ss += buf[j].x * buf[j].x + buf[j].y * buf[j].y
                    + buf[j].z * buf[j].z + buf[j].w * buf[j].w;
            }
        } else {
            #pragma unroll
            for (int j = 0; j < 8; j++) buf[j] = make_float4(0.f, 0.f, 0.f, 0.f);
        }
        float tot = ss + __shfl_xor(ss, 1, 64);
        tot += __shfl_xor(tot, 2, 64);           // lanes 4r..4r+3 are wave-adjacent
        float rn = (c < CC) ? rsqrtf(tot) : 0.f;
        #pragma unroll
        for (int j = 0; j < 4; j++) {
            __hip_bfloat16 tmp[8];
            float4 a = buf[2 * j], b2 = buf[2 * j + 1];
            tmp[0] = __float2bfloat16(a.x * rn);
            tmp[1] = __float2bfloat16(a.y * rn);
            tmp[2] = __float2bfloat16(a.z * rn);
            tmp[3] = __float2bfloat16(a.w * rn);
            tmp[4] = __float2bfloat16(b2.x * rn);
            tmp[5] = __float2bfloat16(b2.y * rn);
            tmp[6] = __float2bfloat16(b2.z * rn);
            tmp[7] = __float2bfloat16(b2.w * rn);
            *(uint4*)(&Bs[r][h * 32 + j * 8]) = *(const uint4*)tmp;
        }
    }
    __syncthreads();   // Bs visible

    int wave = tid >> 6;
    int lane = tid & 63;
    int lrow = lane & 15;
    int lquad = lane >> 4;

    // ---- hoist this wave's class fragments (loop-invariant): 16 VGPRs ----
    short8 cf[4];
    #pragma unroll
    for (int ks = 0; ks < 4; ks++)
        cf[ks] = *(const short8*)(&Bs[wave * 16 + lrow][ks * 32 + lquad * 8]);

    int cq = c0 + wave * 16 + lquad * 4;     // this lane's 4 output classes
    bool cok = cq < CC;                      // CC%4==0 -> whole float4 valid or invalid

    for (int rb = 0; rb < BB / BLK_M; rb++) {
        // ---- stage A tile (64x128 bf16 = 1024 uint4, 4 per thread) ----
        {
            const uint4* src = (const uint4*)(exb + (size_t)rb * BLK_M * DD);
            #pragma unroll
            for (int j = 0; j < 4; j++) {
                int i = tid + j * 256;
                int r = i >> 4, kc = i & 15;
                *(uint4*)(&As[r][kc * 8]) = src[i];
            }
        }
        __syncthreads();   // A staged

        // ---- swapped MFMA: acc[bt] covers batch rows bt*16..+15, this wave's 16 classes ----
        float4v acc[4];
        #pragma unroll
        for (int bt = 0; bt < 4; bt++) acc[bt] = (float4v)(0.0f);

        #pragma unroll
        for (int ks = 0; ks < 4; ks++) {
            int k0 = ks * 32 + lquad * 8;
            #pragma unroll
            for (int bt = 0; bt < 4; bt++) {
                short8 af = *(const short8*)(&As[bt * 16 + lrow][k0]);
                acc[bt] = __builtin_amdgcn_mfma_f32_16x16x32_bf16(cf[ks], af, acc[bt], 0, 0, 0);
            }
        }
        __syncthreads();   // all As reads done -> next stage may overwrite
                           // (epilogue below overlaps other waves' next staging)

        // ---- register epilogue + plain cached float4 stores ----
        // out = SCALE*( onehot*a + (1-onehot)*(rw*cos + rw - 1) ), rw = ALPHA*exp(-(cos-a)^2/2)
        if (cok) {
            #pragma unroll
            for (int bt = 0; bt < 4; bt++) {
                int b = rb * BLK_M + bt * 16 + lrow;
                float a = alb[b];
                int lab = labels[b];
                float4v res;
                #pragma unroll
                for (int e = 0; e < 4; e++) {
                    float cosv = acc[bt][e];
                    float d = cosv - a;
                    float rw = ALPHA_F * __expf(-0.5f * d * d);
                    res[e] = (cq + e == lab) ? SCALE_F * a
                                             : SCALE_F * (rw * cosv + rw - 1.0f);
                }
                *(float4v*)(out + (size_t)b * CC + cq) = res;
            }
        }
    }
}

extern "C" void kernel_launch(void* const* d_in, const int* in_sizes, int n_in,
                              void* d_out, int out_size, void* d_ws, size_t ws_size,
                              hipStream_t stream) {
    const float* feats  = (const float*)d_in[0];
    const int*   labels = (const int*)d_in[1];
    const float* weight = (const float*)d_in[2];
    float* out = (float*)d_out;

    char* ws = (char*)d_ws;
    __hip_bfloat16* exb = (__hip_bfloat16*)ws;            // 512*128*2 = 131072 B
    float* alb = (float*)(ws + 131072);                   // 2048 B

    hipLaunchKernelGGL(k_prep, dim3(BB), dim3(64), 0, stream,
                       feats, weight, labels, exb, alb);

    dim3 grid((CC + BLK_N - 1) / BLK_N);                  // 1563 column tiles
    hipLaunchKernelGGL(k_main, grid, dim3(256), 0, stream,
                       exb, weight, alb, labels, out);
}